// Round 15
// baseline (27.349 us; speedup 1.0000x reference)
//
#include <hip/hip_runtime.h>

// PixelEffectModule: 8-bin intensity histogram over 11x11 windows at stride 8,
// argmax bin, output that bin's mean RGB, upsampled 8x8.
// Input: rgb (1,3,2048,2048) fp32 in [0,255). Output: (1,3,2048,2048) fp32.
//
// R15: single-wave pipelined WG. R12/R14 (~25.5 us both) showed cross-WG
// statistical overlap is exhausted: each WG is stage->drain->compute serial
// and co-launched WGs phase-align. Here one 64-lane wave owns an 8-cell tile
// (8 cells x 8 row-band parts; reduces = shfl_xor(8/16/32), NO LDS reduce,
// NO __syncthreads anywhere) and walks 4 vertically-adjacent tiles with
// double-buffered LDS + counted vmcnt (T3/T4): stage(t+1) issues before
// compute(t); in-order vmcnt retirement gives exact waits (10/16/16/6,
// global stores included in the counts). DMA latency hides under the SAME
// wave's compute. 2x10KB LDS -> 8 WG/CU. Vertical adjacency = halo rows
// L2-hot. Math path byte-identical to R14 (bins, packed-u64 counts, nibble
// cache, argmax, row writes; absmax 0.0 lineage).
// Tripwires: absmax!=0 -> vmcnt race, revert; WRITE>60MB -> spill (breaks
// vmcnt counts too); dur>=25 -> structure fails, plateau.

#define Wd 2048
#define HW (2048 * 2048)
#define CPR 19              // 16B chunks per staged row (76 floats, odd->bank derot)
#define CPC (11 * CPR)      // 209 chunks per channel
#define NCHK (3 * CPC)      // 627 chunks per tile
#define BUFC 640            // padded chunks per buffer (10 DMA iters x 64)
#define BUF_F (BUFC * 4)    // 2560 floats = 10240 B

typedef unsigned int u32;
typedef unsigned long long u64;
typedef float f32x4 __attribute__((ext_vector_type(4)));

// correctly-rounded t/3 (Markstein), 3 ops vs ~9-inst div expansion
__device__ __forceinline__ float div3(float t) {
    const float c = 0x1.555556p-2f;  // RN(1/3)
    float q0 = t * c;
    float r  = __builtin_fmaf(q0, -3.0f, t);
    return __builtin_fmaf(r, c, q0);
}

// chunk swizzle: involution on [0,16), identity on 16..18 (stays in-row)
__device__ __forceinline__ u32 swzc(u32 w) {
    return (w < 16u) ? (w ^ ((w >> 3) & 3u)) : w;
}

// issue 10 global_load_lds for one tile (linear LDS dest, pre-swz source)
__device__ __forceinline__ void stage_tile(const float* __restrict__ rgb,
                                           float* buf, int lane,
                                           int xstart, int ytop) {
#pragma unroll
    for (int it = 0; it < 10; ++it) {
        u32 cbase = (u32)it * 64u;                     // wave-uniform
        u32 c = cbase + (u32)lane;
        c = c < (u32)(NCHK - 1) ? c : (u32)(NCHK - 1); // clamp -> junk chunk
        u32 ch  = (c >= 2u * CPC) ? 2u : (c >= (u32)CPC ? 1u : 0u);
        u32 rem = c - ch * (u32)CPC;
        u32 row = rem / (u32)CPR;
        u32 wph = rem - row * (u32)CPR;                // physical chunk-in-row
        u32 wlog = swzc(wph);                          // logical chunk to fetch
        int y = ytop + (int)row; y = y < 0 ? 0 : y;    // clamped rows unread
        long o = (long)ch * HW + (long)y * Wd
               + (long)(xstart + (int)(wlog * 4u));
        long omax = 3L * HW - 4;                       // right-edge last-row clamp
        o = o < omax ? o : omax;                       // (clamped chunk unread)
        float* ldst = buf + cbase * 4u;                // wave-uniform base
        __builtin_amdgcn_global_load_lds(
            (const __attribute__((address_space(1))) void*)(rgb + o),
            (__attribute__((address_space(3))) void*)ldst, 16, 0, 0);
    }
}

// one tile's full compute from staged LDS (R14 math path, wave-local reduces)
__device__ __forceinline__ void compute_tile(const float* __restrict__ buf,
                                             float* __restrict__ out,
                                             int p, int cl, int ox, int oy,
                                             int w0, u32 vmask) {
    const int ytop = oy * 8 - 5;
    const int rs = (p < 3) ? 2 * p : (3 + p);  // first window-row of this part
    const int nr = (p < 3) ? 2 : 1;            // rows: 2,2,2,1,1,1,1,1

#define LOADROW(dst, chn, rr)                                                   \
    {                                                                           \
        int rb_ = ((chn) * 11 + (rr)) * CPR;                                    \
        *(f32x4*)((dst) + 0)  = *(const f32x4*)&buf[(u32)(rb_ + swzc(w0+0))*4u];\
        *(f32x4*)((dst) + 4)  = *(const f32x4*)&buf[(u32)(rb_ + swzc(w0+1))*4u];\
        *(f32x4*)((dst) + 8)  = *(const f32x4*)&buf[(u32)(rb_ + swzc(w0+2))*4u];\
        *(f32x4*)((dst) + 12) = *(const f32x4*)&buf[(u32)(rb_ + swzc(w0+3))*4u];\
    }

    // ---- pass 1: bin pixels, packed byte counts + nibble cache ----
    u64 c64 = 0;
    u32 nbl[2], nbh[2];
#pragma unroll
    for (int k = 0; k < 2; ++k) {
        nbl[k] = 0xFFFFFFFFu; nbh[k] = 0xFFFFFFFFu;
        int r = rs + k;
        int y = ytop + r;
        if (k < nr && y >= 0) {
            float vR[16], vG[16], vB[16];
            LOADROW(vR, 0, r) LOADROW(vG, 1, r) LOADROW(vB, 2, r)
            u32 bl = 0, bh = 0;
#pragma unroll
            for (int j = 0; j < 14; ++j) {
                float m = div3(vR[j] + vG[j] + vB[j]);
                u32 bin = (u32)(m * 0.03125f);     // trunc(mean/32), exact
                u32 valid = (vmask >> j) & 1u;
                c64 += (u64)valid << (bin << 3);
                u32 binv = valid ? bin : 15u;      // 15 matches no bin
                if (j < 8) bl |= binv << (4 * j);
                else       bh |= binv << (4 * (j - 8));
            }
            nbl[k] = bl; nbh[k] = bh;
        }
    }

    // ---- reduce counts across the 8 parts (lane bits 3,4,5) ----
    c64 += __shfl_xor(c64, 8);
    c64 += __shfl_xor(c64, 16);
    c64 += __shfl_xor(c64, 32);

    u32 lo = (u32)c64, hi = (u32)(c64 >> 32);
    u32 best = 0, bc = lo & 0xFFu;
#pragma unroll
    for (int b = 1; b < 8; ++b) {
        u32 cb = ((b < 4 ? lo : hi) >> ((b & 3) * 8)) & 0xFFu;
        bool t = cb > bc;
        bc   = t ? cb : bc;
        best = t ? (u32)b : best;
    }

    // ---- pass 2: re-read LDS, sum winning bin via nibbles ----
    float sr = 0.f, sg = 0.f, sb = 0.f;
#pragma unroll
    for (int k = 0; k < 2; ++k) {
        int r = rs + k;
        int y = ytop + r;
        if (k < nr && y >= 0) {
            float vR[16], vG[16], vB[16];
            LOADROW(vR, 0, r) LOADROW(vG, 1, r) LOADROW(vB, 2, r)
            u32 bl = nbl[k], bh = nbh[k];
#pragma unroll
            for (int j = 0; j < 14; ++j) {
                u32 bin = ((j < 8) ? (bl >> (4 * j))
                                   : (bh >> (4 * (j - 8)))) & 0xFu;
                float hm = (bin == best) ? 1.0f : 0.0f;
                sr = __builtin_fmaf(hm, vR[j], sr);
                sg = __builtin_fmaf(hm, vG[j], sg);
                sb = __builtin_fmaf(hm, vB[j], sb);
            }
        }
    }
    sr += __shfl_xor(sr, 8); sr += __shfl_xor(sr, 16); sr += __shfl_xor(sr, 32);
    sg += __shfl_xor(sg, 8); sg += __shfl_xor(sg, 16); sg += __shfl_xor(sg, 32);
    sb += __shfl_xor(sb, 8); sb += __shfl_xor(sb, 16); sb += __shfl_xor(sb, 32);

    float fbc = (float)bc;
    float orv = sr / fbc, ogv = sg / fbc, obv = sb / fbc;

    // ---- write: part p owns row p of the 8x8 block, 2x float4 per channel ----
    size_t base = (size_t)(oy * 8 + p) * Wd + (size_t)(ox * 8);
    float vals[3] = { orv, ogv, obv };
#pragma unroll
    for (int c = 0; c < 3; ++c) {
        float v = vals[c];
        float4 vv = make_float4(v, v, v, v);
        float* o = out + (size_t)c * HW + base;
        ((float4*)o)[0] = vv;
        ((float4*)o)[1] = vv;
    }
#undef LOADROW
}

#define VMWAIT(N)                                         \
    asm volatile("s_waitcnt vmcnt(" #N ")" ::: "memory"); \
    __builtin_amdgcn_sched_barrier(0)

__global__ __launch_bounds__(64, 2)
void pixel_effect_kernel(const float* __restrict__ rgb, float* __restrict__ out) {
    __shared__ float lds0[BUF_F];
    __shared__ float lds1[BUF_F];

    const int lane = threadIdx.x;          // single wave per WG
    const int p  = lane >> 3;              // row-band part 0..7
    const int cl = lane & 7;               // cell within 8-strip

    // XCD swizzle (grid 2048 = 8*256, bijective): XCD (wgid&7) owns
    // s in [256*xcd, 256*xcd+256) = 4 contiguous x-strips, all rows.
    u32 wgid = blockIdx.x;
    u32 s = (wgid & 7u) * 256u + (wgid >> 3);
    const int strip  = (int)(s >> 6);          // x-strip 0..31
    const int rowb   = (int)(s & 63u) * 4;     // 4 consecutive cell-rows
    const int xstart = strip ? strip * 64 - 8 : 0;
    const int ox     = strip * 8 + cl;
    const int lx_off = (ox == 0) ? 0 : (8 * ox - 8 - xstart);
    const int w0     = lx_off >> 2;
    const u32 vmask  = (ox == 0) ? 0x003Fu : 0x3FF8u;

    // ---- 4-tile rolling pipeline, counted vmcnt (in-order retirement) ----
    stage_tile(rgb, lds0, lane, xstart, (rowb + 0) * 8 - 5);   // out: 10

    stage_tile(rgb, lds1, lane, xstart, (rowb + 1) * 8 - 5);   // out: 20
    VMWAIT(10);                               // tile0 loads done, tile1 in flight
    compute_tile(lds0, out, p, cl, ox, rowb + 0, w0, vmask);   // +6 stores

    stage_tile(rgb, lds0, lane, xstart, (rowb + 2) * 8 - 5);
    VMWAIT(16);                               // tile1 done (oldest: t1=10, st0=6 ...)
    compute_tile(lds1, out, p, cl, ox, rowb + 1, w0, vmask);

    stage_tile(rgb, lds1, lane, xstart, (rowb + 3) * 8 - 5);
    VMWAIT(16);                               // tile2 done (st0+t2 retired)
    compute_tile(lds0, out, p, cl, ox, rowb + 2, w0, vmask);

    VMWAIT(6);                                // tile3 done (st2 may remain)
    compute_tile(lds1, out, p, cl, ox, rowb + 3, w0, vmask);
}

extern "C" void kernel_launch(void* const* d_in, const int* in_sizes, int n_in,
                              void* d_out, int out_size, void* d_ws, size_t ws_size,
                              hipStream_t stream) {
    const float* rgb = (const float*)d_in[0];
    float* out = (float*)d_out;
    dim3 block(64, 1, 1);                 // 1 wave = 1 tile pipeline
    dim3 grid(2048, 1, 1);                // 32 strips x 64 row-groups (swizzled)
    hipLaunchKernelGGL(pixel_effect_kernel, grid, block, 0, stream, rgb, out);
}